// Round 9
// baseline (291.921 us; speedup 1.0000x reference)
//
#include <hip/hip_runtime.h>

// B=4, DIN=DM=256, N=256, L=64, H=4, LH=16.
// Round-9: SPLIT kernels. A: projections (b,n,hp)->q^T,k^T,v in ws (bf16, blocked
// layouts identical to the r2/r8-verified LDS layouts). B: attention+out-proj with
// q-frags read per-lane from ws, K/V linear-copied to LDS; 2 barriers.
// Fallback to the r8 fused kernel if ws_size < ~101MB.
// BANNED (measured): inline-asm cvt_pk (r3/r4 corruption), __launch_bounds__ min-
// clause (r6/r7 spills).

typedef unsigned int u32;
typedef unsigned short u16;
typedef __attribute__((ext_vector_type(8))) short s8v;    // 8 x bf16
typedef __attribute__((ext_vector_type(16))) float f16v;  // 16 x f32 acc

#define QSCALE 0.360673760222f   // 0.25 * log2(e)

// ---- ws layout (u16 units) ----
// [0, 262144): weights bf16 (Wq,Wk,Wv,Wo)
// [262144, +2048*8192): Q blocks   (per blk: [lblk4][o256][j8])
// [.., +2048*16384): KV blocks     (per blk: KT 8192 then VT 8192)
#define WS_Q 262144
#define WS_KV (262144 + 2048 * 8192)
#define WS_NEED_BYTES (2ull * (262144ull + 2048ull * 8192ull + 2048ull * 16384ull))

__device__ __forceinline__ u16 f2bf(float x) {          // RNE bit-twiddle (verified)
  union { float f; u32 u; } c; c.f = x;
  return (u16)((c.u + 0x7FFFu + ((c.u >> 16) & 1u)) >> 16);
}
__device__ __forceinline__ u32 pk2(float a, float b) {  // lo=a, hi=b (verified)
  return (u32)f2bf(a) | ((u32)f2bf(b) << 16);
}
__device__ __forceinline__ float xh_max(float v) { return fmaxf(v, __shfl_xor(v, 32)); }
__device__ __forceinline__ float xh_sum(float v) { return v + __shfl_xor(v, 32); }

__global__ void cvt_weights(const float* __restrict__ wq, const float* __restrict__ wk,
                            const float* __restrict__ wv, const float* __restrict__ wo,
                            u16* __restrict__ out) {
  int i = blockIdx.x * 256 + threadIdx.x;  // 0..65535
  out[i]          = f2bf(wq[i]);
  out[i + 65536]  = f2bf(wk[i]);
  out[i + 131072] = f2bf(wv[i]);
  out[i + 196608] = f2bf(wo[i]);
}

// ======================= Kernel A: projections =======================
// LDS: AXS [cblk32][l32][j8] @0 (8192), ALIN linear staging @8192 (9216)
#define AXS 0
#define ALIN 8192
#define A_LDS 17408
#define LSTR 36

__device__ __forceinline__ void stage_lin(const float* __restrict__ src, u16* lds,
                                          int tid) {
#pragma unroll
  for (int it = 0; it < 4; ++it) {
    int f4 = it * 512 + tid;           // 0..2047 float4s
    int c = f4 >> 3;
    int l4 = (f4 & 7) << 2;
    const float4 v = *reinterpret_cast<const float4*>(src + c * 16384 + l4);
    uint2 w; w.x = pk2(v.x, v.y); w.y = pk2(v.z, v.w);
    *reinterpret_cast<uint2*>(&lds[ALIN + c * LSTR + l4]) = w;
  }
}

__device__ __forceinline__ void lin_to_xs(u16* lds, int tid) {
#pragma unroll
  for (int it = 0; it < 2; ++it) {
    int idx = it * 512 + tid;          // (cblk, l)
    int l = idx & 31, cb = idx >> 5;
    int sb = ALIN + cb * (8 * LSTR) + l;
    u32 u0 = (u32)lds[sb]            | ((u32)lds[sb + LSTR]     << 16);
    u32 u1 = (u32)lds[sb + 2 * LSTR] | ((u32)lds[sb + 3 * LSTR] << 16);
    u32 u2 = (u32)lds[sb + 4 * LSTR] | ((u32)lds[sb + 5 * LSTR] << 16);
    u32 u3 = (u32)lds[sb + 6 * LSTR] | ((u32)lds[sb + 7 * LSTR] << 16);
    union { u32 u[4]; s8v v; } pw;
    pw.u[0] = u0; pw.u[1] = u1; pw.u[2] = u2; pw.u[3] = u3;
    *reinterpret_cast<s8v*>(&lds[AXS + cb * 256 + l * 8]) = pw.v;
  }
}

// q^T/k^T: D[l][o] = (sum_c X^T[l][c] W[o][c] + b[o]) * osc -> global dst [lblk][o][j]
__device__ __forceinline__ void projT_g(u16* lds, const u16* __restrict__ w,
                                        const float* __restrict__ bias,
                                        u16* __restrict__ dst, float osc,
                                        int wid, int lo, int hi) {
  const int o = wid * 32 + lo;
  f16v a;
#pragma unroll
  for (int i = 0; i < 16; ++i) a[i] = 0.f;
#pragma unroll
  for (int s = 0; s < 16; ++s) {
    const s8v bw = *reinterpret_cast<const s8v*>(w + o * 256 + s * 16 + hi * 8);
    const s8v xf = *reinterpret_cast<const s8v*>(&lds[AXS + (2 * s + hi) * 256 + lo * 8]);
    a = __builtin_amdgcn_mfma_f32_32x32x16_bf16(xf, bw, a, 0, 0, 0);
  }
  const float bb = bias[o];
#pragma unroll
  for (int g = 0; g < 4; ++g) {
    uint2 wv2;
    wv2.x = pk2((a[4 * g + 0] + bb) * osc, (a[4 * g + 1] + bb) * osc);
    wv2.y = pk2((a[4 * g + 2] + bb) * osc, (a[4 * g + 3] + bb) * osc);
    *reinterpret_cast<uint2*>(dst + g * 2048 + o * 8 + hi * 4) = wv2;
  }
}

// v: D[e][l] -> global dst [eblk][l][j]
__device__ __forceinline__ void projV_g(u16* lds, const u16* __restrict__ w,
                                        const float* __restrict__ bias,
                                        u16* __restrict__ dst,
                                        int wid, int lo, int hi) {
  const int e0 = wid * 32;
  const int e = e0 + lo;
  f16v a;
#pragma unroll
  for (int i = 0; i < 16; ++i) a[i] = 0.f;
#pragma unroll
  for (int s = 0; s < 16; ++s) {
    const s8v aw = *reinterpret_cast<const s8v*>(w + e * 256 + s * 16 + hi * 8);
    const s8v xf = *reinterpret_cast<const s8v*>(&lds[AXS + (2 * s + hi) * 256 + lo * 8]);
    a = __builtin_amdgcn_mfma_f32_32x32x16_bf16(aw, xf, a, 0, 0, 0);
  }
#pragma unroll
  for (int g = 0; g < 4; ++g) {
    const int eb = e0 + 8 * g + 4 * hi;
    uint2 wv2;
    wv2.x = pk2(a[4 * g + 0] + bias[eb + 0], a[4 * g + 1] + bias[eb + 1]);
    wv2.y = pk2(a[4 * g + 2] + bias[eb + 2], a[4 * g + 3] + bias[eb + 3]);
    *reinterpret_cast<uint2*>(dst + (4 * wid + g) * 256 + lo * 8 + hi * 4) = wv2;
  }
}

__global__ __launch_bounds__(512)
void proj_kernel(const float* __restrict__ xq, const float* __restrict__ xk,
                 const float* __restrict__ xv, const u16* __restrict__ wb,
                 const float* __restrict__ bq, const float* __restrict__ bk,
                 const float* __restrict__ bv, u16* __restrict__ ws) {
  __shared__ __align__(16) u16 lds[A_LDS];
  const int tid = threadIdx.x;
  const int lane = tid & 63;
  const int wid = tid >> 6;
  const int lo = lane & 31;
  const int hi = lane >> 5;
  const long blk = blockIdx.x;
  const int hp = blockIdx.x & 1;
  const int n = (blockIdx.x >> 1) & 255;
  const int b = blockIdx.x >> 9;
  const long base = (long)b * 4194304 + n * 64 + hp * 32;

  u16* wq_dst = ws + WS_Q + blk * 8192;
  u16* wk_dst = ws + WS_KV + blk * 16384;
  u16* wv_dst = wk_dst + 8192;

  stage_lin(xq + base, lds, tid);
  __syncthreads();
  lin_to_xs(lds, tid);
  __syncthreads();
  stage_lin(xk + base, lds, tid);                       // overlaps proj q
  projT_g(lds, wb + 0, bq, wq_dst, QSCALE, wid, lo, hi);
  __syncthreads();
  lin_to_xs(lds, tid);
  __syncthreads();
  stage_lin(xv + base, lds, tid);                       // overlaps proj k
  projT_g(lds, wb + 65536, bk, wk_dst, 1.0f, wid, lo, hi);
  __syncthreads();
  lin_to_xs(lds, tid);
  __syncthreads();
  projV_g(lds, wb + 131072, bv, wv_dst, wid, lo, hi);
}

// ======================= Kernel B: attention + out-proj =======================
// LDS: BKT @0 (8192), BVT @8192 (8192), BATT @16384 (8192)
#define BKT 0
#define BVT 8192
#define BATT 16384
#define B_LDS 24576

__device__ __forceinline__ void proj_O(u16* lds, int xs, const u16* __restrict__ w,
                                       const float* __restrict__ bias,
                                       float* __restrict__ out, long obase,
                                       int wid, int lo, int hi) {
  const int o0 = wid * 32;
  const int o = o0 + lo;
  f16v a;
#pragma unroll
  for (int i = 0; i < 16; ++i) a[i] = 0.f;
#pragma unroll
  for (int s = 0; s < 16; ++s) {
    const s8v aw = *reinterpret_cast<const s8v*>(w + o * 256 + s * 16 + hi * 8);
    const s8v bf = *reinterpret_cast<const s8v*>(&lds[xs + (2 * s + hi) * 256 + lo * 8]);
    a = __builtin_amdgcn_mfma_f32_32x32x16_bf16(aw, bf, a, 0, 0, 0);
  }
#pragma unroll
  for (int r = 0; r < 16; ++r) {
    const int orow = o0 + (r & 3) + 8 * (r >> 2) + 4 * hi;
    out[obase + orow * 16384 + lo] = a[r] + bias[orow];
  }
}

__global__ __launch_bounds__(512)
void attn_kernel(const u16* __restrict__ ws, const float* __restrict__ bo,
                 float* __restrict__ out) {
  __shared__ __align__(16) u16 lds[B_LDS];
  const int tid = threadIdx.x;
  const int lane = tid & 63;
  const int wid = tid >> 6;
  const int lo = lane & 31;
  const int hi = lane >> 5;
  const long blk = blockIdx.x;
  const int hp = blockIdx.x & 1;
  const int n = (blockIdx.x >> 1) & 255;
  const int b = blockIdx.x >> 9;
  const long base = (long)b * 4194304 + n * 64 + hp * 32;

  // cooperative linear copy: KT+VT (16384 u16 = 2048 uint4)
  const uint4* src = reinterpret_cast<const uint4*>(ws + WS_KV + blk * 16384);
  uint4* dst = reinterpret_cast<uint4*>(lds);
#pragma unroll
  for (int i = 0; i < 4; ++i) dst[i * 512 + tid] = src[i * 512 + tid];

  // q frags: per-lane 16B global loads (layout = A's projT_g output)
  const u16* qsrc = ws + WS_Q + blk * 8192;
  s8v qf[2];
  qf[0] = *reinterpret_cast<const s8v*>(qsrc + (0 + hi) * 2048 + (wid * 32 + lo) * 8);
  qf[1] = *reinterpret_cast<const s8v*>(qsrc + (2 + hi) * 2048 + (wid * 32 + lo) * 8);
  __syncthreads();                                   // 1: KT/VT ready

  f16v z16;
#pragma unroll
  for (int i = 0; i < 16; ++i) z16[i] = 0.f;
  const int l15 = lane & 15;

#pragma unroll
  for (int h = 0; h < 2; ++h) {
    float m = 0.f, sm = 0.f;
    f16v ot;
#pragma unroll
    for (int i = 0; i < 16; ++i) ot[i] = 0.f;

#pragma unroll
    for (int et = 0; et < 8; ++et) {
      const s8v kf = *reinterpret_cast<const s8v*>(
          &lds[BKT + (2 * h + hi) * 2048 + (et * 32 + lo) * 8]);
      f16v st = __builtin_amdgcn_mfma_f32_32x32x16_bf16(kf, qf[h], z16, 0, 0, 0);

      float t[8];
#pragma unroll
      for (int i = 0; i < 8; ++i) t[i] = fmaxf(st[i], st[i + 8]);
#pragma unroll
      for (int i = 0; i < 4; ++i) t[i] = fmaxf(t[i], t[i + 4]);
      const float tm = xh_max(fmaxf(fmaxf(t[0], t[1]), fmaxf(t[2], t[3])));

      if (et == 0) {
        m = tm;                          // peel
      } else {
        const float mn = fmaxf(m, tm);
        const float f = __builtin_amdgcn_exp2f(m - mn);
        m = mn;
        sm *= f;
#pragma unroll
        for (int i = 0; i < 16; ++i) ot[i] *= f;
      }
#pragma unroll
      for (int i = 0; i < 16; ++i) st[i] = __builtin_amdgcn_exp2f(st[i] - m);
      float s[8];
#pragma unroll
      for (int i = 0; i < 8; ++i) s[i] = st[i] + st[i + 8];
#pragma unroll
      for (int i = 0; i < 4; ++i) s[i] = s[i] + s[i + 4];
      sm += (s[0] + s[1]) + (s[2] + s[3]);

#pragma unroll
      for (int s2 = 0; s2 < 2; ++s2) {
        const int ks = 2 * et + s2;
        const s8v vf = *reinterpret_cast<const s8v*>(
            &lds[BVT + (2 * ks + hi) * 256 + (h * 16 + l15) * 8]);
        const int q = s2 * 8;
        const u32 x0 = pk2(st[q + 0], st[q + 1]);
        const u32 x1 = pk2(st[q + 2], st[q + 3]);
        const u32 y0 = pk2(st[q + 4], st[q + 5]);
        const u32 y1 = pk2(st[q + 6], st[q + 7]);
        const u32 z0 = hi ? x0 : y0;
        const u32 z1 = hi ? x1 : y1;
        const u32 s0 = (u32)__shfl_xor((int)z0, 32);
        const u32 s1 = (u32)__shfl_xor((int)z1, 32);
        union { u32 u[4]; s8v v; } bu;
        bu.u[0] = hi ? s0 : x0;
        bu.u[1] = hi ? s1 : x1;
        bu.u[2] = hi ? y0 : s0;
        bu.u[3] = hi ? y1 : s1;
        ot = __builtin_amdgcn_mfma_f32_32x32x16_bf16(vf, bu.v, ot, 0, 0, 0);
      }
    }
    const float rinv = 1.0f / xh_sum(sm);
    const int d = wid * 32 + lo;
#pragma unroll
    for (int r = 0; r < 8; ++r) {
      const int lh = (r & 3) + 8 * (r >> 2) + 4 * hi;   // 0..15
      const int l = h * 16 + lh;
      lds[BATT + (d >> 3) * 256 + l * 8 + (d & 7)] = f2bf(ot[r] * rinv);
    }
  }
  __syncthreads();                                   // 2: ATT ready

  proj_O(lds, BATT, reinterpret_cast<const u16*>(ws) + 196608, bo, out, base, wid, lo, hi);
}

// ======================= Fallback: r8 fused kernel (passing) =======================
#define XS0 0
#define XS1 8192
#define KT 16384
#define VT 24576
#define LDS_TOT 32768

__device__ __forceinline__ void stage_blk(const float* __restrict__ src, u16* lds,
                                          int dstoff, int tid) {
#pragma unroll
  for (int it = 0; it < 2; ++it) {
    const int idx = it * 512 + tid;
    const int l = idx & 31, cb = idx >> 5;
    const float* p = src + (cb * 8) * 16384 + l;
    float x[8];
#pragma unroll
    for (int j = 0; j < 8; ++j) x[j] = p[j * 16384];
    union { u32 u[4]; s8v v; } pw;
    pw.u[0] = pk2(x[0], x[1]);
    pw.u[1] = pk2(x[2], x[3]);
    pw.u[2] = pk2(x[4], x[5]);
    pw.u[3] = pk2(x[6], x[7]);
    *reinterpret_cast<s8v*>(&lds[dstoff + cb * 256 + l * 8]) = pw.v;
  }
}

__device__ __forceinline__ void proj_Q(u16* lds, int xs, const u16* __restrict__ w,
                                       const float* __restrict__ bias,
                                       s8v qf[2], int wid, int lo, int hi) {
  const int o = wid * 32 + lo;
  f16v a;
#pragma unroll
  for (int i = 0; i < 16; ++i) a[i] = 0.f;
#pragma unroll
  for (int s = 0; s < 16; ++s) {
    const s8v bw = *reinterpret_cast<const s8v*>(w + o * 256 + s * 16 + hi * 8);
    const s8v xf = *reinterpret_cast<const s8v*>(&lds[xs + (2 * s + hi) * 256 + lo * 8]);
    a = __builtin_amdgcn_mfma_f32_32x32x16_bf16(xf, bw, a, 0, 0, 0);
  }
  const float bb = bias[o];
  u32 W[8];
#pragma unroll
  for (int g = 0; g < 4; ++g) {
    W[2 * g]     = pk2((a[4 * g + 0] + bb) * QSCALE, (a[4 * g + 1] + bb) * QSCALE);
    W[2 * g + 1] = pk2((a[4 * g + 2] + bb) * QSCALE, (a[4 * g + 3] + bb) * QSCALE);
  }
#pragma unroll
  for (int h = 0; h < 2; ++h) {
    const int bse = 4 * h;
    const u32 z0 = hi ? W[bse + 0] : W[bse + 2];
    const u32 z1 = hi ? W[bse + 1] : W[bse + 3];
    const u32 s0 = (u32)__shfl_xor((int)z0, 32);
    const u32 s1 = (u32)__shfl_xor((int)z1, 32);
    union { u32 u[4]; s8v v; } fu;
    fu.u[0] = hi ? s0 : W[bse + 0];
    fu.u[1] = hi ? s1 : W[bse + 1];
    fu.u[2] = hi ? W[bse + 2] : s0;
    fu.u[3] = hi ? W[bse + 3] : s1;
    qf[h] = fu.v;
  }
}

__device__ __forceinline__ void proj_K(u16* lds, int xs, const u16* __restrict__ w,
                                       const float* __restrict__ bias,
                                       int wid, int lo, int hi) {
  const int o = wid * 32 + lo;
  f16v a;
#pragma unroll
  for (int i = 0; i < 16; ++i) a[i] = 0.f;
#pragma unroll
  for (int s = 0; s < 16; ++s) {
    const s8v bw = *reinterpret_cast<const s8v*>(w + o * 256 + s * 16 + hi * 8);
    const s8v xf = *reinterpret_cast<const s8v*>(&lds[xs + (2 * s + hi) * 256 + lo * 8]);
    a = __builtin_amdgcn_mfma_f32_32x32x16_bf16(xf, bw, a, 0, 0, 0);
  }
  const float bb = bias[o];
#pragma unroll
  for (int g = 0; g < 4; ++g) {
    uint2 wv2;
    wv2.x = pk2(a[4 * g + 0] + bb, a[4 * g + 1] + bb);
    wv2.y = pk2(a[4 * g + 2] + bb, a[4 * g + 3] + bb);
    *reinterpret_cast<uint2*>(&lds[KT + g * 2048 + o * 8 + hi * 4]) = wv2;
  }
}

__device__ __forceinline__ void proj_V(u16* lds, int xs, const u16* __restrict__ w,
                                       const float* __restrict__ bias,
                                       int wid, int lo, int hi) {
  const int e0 = wid * 32;
  const int e = e0 + lo;
  f16v a;
#pragma unroll
  for (int i = 0; i < 16; ++i) a[i] = 0.f;
#pragma unroll
  for (int s = 0; s < 16; ++s) {
    const s8v aw = *reinterpret_cast<const s8v*>(w + e * 256 + s * 16 + hi * 8);
    const s8v xf = *reinterpret_cast<const s8v*>(&lds[xs + (2 * s + hi) * 256 + lo * 8]);
    a = __builtin_amdgcn_mfma_f32_32x32x16_bf16(aw, xf, a, 0, 0, 0);
  }
#pragma unroll
  for (int g = 0; g < 4; ++g) {
    const int eb = e0 + 8 * g + 4 * hi;
    uint2 wv2;
    wv2.x = pk2(a[4 * g + 0] + bias[eb + 0], a[4 * g + 1] + bias[eb + 1]);
    wv2.y = pk2(a[4 * g + 2] + bias[eb + 2], a[4 * g + 3] + bias[eb + 3]);
    *reinterpret_cast<uint2*>(&lds[VT + (4 * wid + g) * 256 + lo * 8 + hi * 4]) = wv2;
  }
}

__global__ __launch_bounds__(512)
void mha_kernel(const float* __restrict__ xq, const float* __restrict__ xk,
                const float* __restrict__ xv, const u16* __restrict__ wb,
                const float* __restrict__ bq, const float* __restrict__ bk,
                const float* __restrict__ bv, const float* __restrict__ bo,
                float* __restrict__ out) {
  __shared__ __align__(16) u16 lds[LDS_TOT];
  const int tid = threadIdx.x;
  const int lane = tid & 63;
  const int wid = tid >> 6;
  const int lo = lane & 31;
  const int hi = lane >> 5;
  const int hp = blockIdx.x & 1;
  const int n = (blockIdx.x >> 1) & 255;
  const int b = blockIdx.x >> 9;
  const long base = (long)b * 4194304 + n * 64 + hp * 32;

  stage_blk(xq + base, lds, XS0, tid);
  __syncthreads();
  s8v qf[2];
  stage_blk(xk + base, lds, XS1, tid);
  proj_Q(lds, XS0, wb + 0, bq, qf, wid, lo, hi);
  __syncthreads();
  stage_blk(xv + base, lds, XS0, tid);
  proj_K(lds, XS1, wb + 65536, bk, wid, lo, hi);
  __syncthreads();
  proj_V(lds, XS0, wb + 131072, bv, wid, lo, hi);
  __syncthreads();

  f16v z16;
#pragma unroll
  for (int i = 0; i < 16; ++i) z16[i] = 0.f;
  const int l15 = lane & 15;

#pragma unroll
  for (int h = 0; h < 2; ++h) {
    float m = 0.f, sm = 0.f;
    f16v ot;
#pragma unroll
    for (int i = 0; i < 16; ++i) ot[i] = 0.f;

#pragma unroll
    for (int et = 0; et < 8; ++et) {
      const s8v kf = *reinterpret_cast<const s8v*>(
          &lds[KT + (2 * h + hi) * 2048 + (et * 32 + lo) * 8]);
      f16v st = __builtin_amdgcn_mfma_f32_32x32x16_bf16(kf, qf[h], z16, 0, 0, 0);

      float t[8];
#pragma unroll
      for (int i = 0; i < 8; ++i) t[i] = fmaxf(st[i], st[i + 8]);
#pragma unroll
      for (int i = 0; i < 4; ++i) t[i] = fmaxf(t[i], t[i + 4]);
      const float tm = xh_max(fmaxf(fmaxf(t[0], t[1]), fmaxf(t[2], t[3])));

      if (et == 0) {
        m = tm;
      } else {
        const float mn = fmaxf(m, tm);
        const float f = __builtin_amdgcn_exp2f(m - mn);
        m = mn;
        sm *= f;
#pragma unroll
        for (int i = 0; i < 16; ++i) ot[i] *= f;
      }
#pragma unroll
      for (int i = 0; i < 16; ++i) st[i] = __builtin_amdgcn_exp2f(st[i] - m);
      float s[8];
#pragma unroll
      for (int i = 0; i < 8; ++i) s[i] = st[i] + st[i + 8];
#pragma unroll
      for (int i = 0; i < 4; ++i) s[i] = s[i] + s[i + 4];
      sm += (s[0] + s[1]) + (s[2] + s[3]);

#pragma unroll
      for (int s2 = 0; s2 < 2; ++s2) {
        const int ks = 2 * et + s2;
        const s8v vf = *reinterpret_cast<const s8v*>(
            &lds[VT + (2 * ks + hi) * 256 + (h * 16 + l15) * 8]);
        const int q = s2 * 8;
        const u32 x0 = pk2(st[q + 0], st[q + 1]);
        const u32 x1 = pk2(st[q + 2], st[q + 3]);
        const u32 y0 = pk2(st[q + 4], st[q + 5]);
        const u32 y1 = pk2(st[q + 6], st[q + 7]);
        const u32 z0 = hi ? x0 : y0;
        const u32 z1 = hi ? x1 : y1;
        const u32 s0 = (u32)__shfl_xor((int)z0, 32);
        const u32 s1 = (u32)__shfl_xor((int)z1, 32);
        union { u32 u[4]; s8v v; } bu;
        bu.u[0] = hi ? s0 : x0;
        bu.u[1] = hi ? s1 : x1;
        bu.u[2] = hi ? y0 : s0;
        bu.u[3] = hi ? y1 : s1;
        ot = __builtin_amdgcn_mfma_f32_32x32x16_bf16(vf, bu.v, ot, 0, 0, 0);
      }
    }
    const float rinv = 1.0f / xh_sum(sm);
    const int d = wid * 32 + lo;
#pragma unroll
    for (int r = 0; r < 8; ++r) {
      const int lh = (r & 3) + 8 * (r >> 2) + 4 * hi;
      const int l = h * 16 + lh;
      lds[XS1 + (d >> 3) * 256 + l * 8 + (d & 7)] = f2bf(ot[r] * rinv);
    }
  }
  __syncthreads();

  proj_O(lds, XS1, wb + 196608, bo, out, base, wid, lo, hi);
}

extern "C" void kernel_launch(void* const* d_in, const int* in_sizes, int n_in,
                              void* d_out, int out_size, void* d_ws, size_t ws_size,
                              hipStream_t stream) {
  const float* xq = (const float*)d_in[0];
  const float* xk = (const float*)d_in[1];
  const float* xv = (const float*)d_in[2];
  const float* wq = (const float*)d_in[3];
  const float* bq = (const float*)d_in[4];
  const float* wk = (const float*)d_in[5];
  const float* bk = (const float*)d_in[6];
  const float* wv = (const float*)d_in[7];
  const float* bv = (const float*)d_in[8];
  const float* wo = (const float*)d_in[9];
  const float* bo = (const float*)d_in[10];
  u16* wsb = (u16*)d_ws;
  float* out = (float*)d_out;

  cvt_weights<<<dim3(256), dim3(256), 0, stream>>>(wq, wk, wv, wo, wsb);
  if (ws_size >= WS_NEED_BYTES) {
    proj_kernel<<<dim3(2048), dim3(512), 0, stream>>>(xq, xk, xv, wsb, bq, bk, bv, wsb);
    attn_kernel<<<dim3(2048), dim3(512), 0, stream>>>(wsb, bo, out);
  } else {
    mha_kernel<<<dim3(2048), dim3(512), 0, stream>>>(xq, xk, xv, wsb, bq, bk, bv, bo, out);
  }
}